// Round 1
// baseline (852.313 us; speedup 1.0000x reference)
//
#include <hip/hip_runtime.h>
#include <hip/hip_bf16.h>

// out[b,s,c] = x[b,s,c] * diagonal[c]
// x: fp32 (8,4096,4096); diagonal: fp32 (4096,); out: fp32 same shape as x.
// Memory-bound elementwise: float4-vectorized grid-stride loop.

__global__ __launch_bounds__(256) void diag_mul_kernel(
    const float4* __restrict__ x,
    const float4* __restrict__ diag,   // diagonal viewed as float4[1024]
    float4* __restrict__ out,
    long long n_vec)                   // total float4 count
{
    const long long stride = (long long)gridDim.x * blockDim.x;
    for (long long i = (long long)blockIdx.x * blockDim.x + threadIdx.x;
         i < n_vec; i += stride) {
        // element index of first lane of this float4 is 4*i; diagonal period C=4096
        // -> diag float4 index = i & (4096/4 - 1) = i & 1023
        float4 xv = x[i];
        float4 dv = diag[i & 1023];
        float4 o;
        o.x = xv.x * dv.x;
        o.y = xv.y * dv.y;
        o.z = xv.z * dv.z;
        o.w = xv.w * dv.w;
        out[i] = o;
    }
}

extern "C" void kernel_launch(void* const* d_in, const int* in_sizes, int n_in,
                              void* d_out, int out_size, void* d_ws, size_t ws_size,
                              hipStream_t stream) {
    const float4* x    = (const float4*)d_in[0];
    const float4* diag = (const float4*)d_in[1];
    float4* out        = (float4*)d_out;

    const long long n_elems = (long long)in_sizes[0];   // 134,217,728
    const long long n_vec   = n_elems / 4;              // divisible: C=4096

    const int block = 256;
    long long want = (n_vec + block - 1) / block;
    int grid = (int)(want < 2048 ? want : 2048);        // 256 CU x 8 blocks

    diag_mul_kernel<<<grid, block, 0, stream>>>(x, diag, out, n_vec);
}